// Round 5
// baseline (1435.492 us; speedup 1.0000x reference)
//
#include <hip/hip_runtime.h>
#include <hip/hip_bf16.h>

#define N_NODES 100000
#define N_EDGES 1600000
#define IN_C 128
#define C 64            // hid_c == out_c
#define SCAN_NB 25      // ceil(N_NODES / 4096)
#define NSLAB 4         // channel slices: 16 ch = 32 B/node = 3.2 MB slab (< 4 MB L2/XCD)
#define MSG_NB (N_NODES / 32)   // 3125 blocks per slab

typedef float vfloat2 __attribute__((ext_vector_type(2)));

__device__ __forceinline__ float bfu2f(unsigned short u) {
    return __uint_as_float(((unsigned int)u) << 16);
}
__device__ __forceinline__ unsigned short f2bfu(float f) {
    __hip_bfloat16 h = __float2bfloat16(f);
    unsigned short u; __builtin_memcpy(&u, &h, 2); return u;
}
// bf16x2 unpack, 1 VALU op each
__device__ __forceinline__ float blo(unsigned int v) { return __uint_as_float(v << 16); }
__device__ __forceinline__ float bhi(unsigned int v) { return __uint_as_float(v & 0xFFFF0000u); }
// 12-bit weight decode: w in [1, ~3.42), rel err ~2.4e-4 (<< bf16's 2e-3)
__device__ __forceinline__ float dec_w12(unsigned int p) {
    return __uint_as_float(((p & 0xFFFu) + 0x3F800u) << 12);
}
__device__ __forceinline__ float load_f(const void* p, int i, int f32) {
    return f32 ? ((const float*)p)[i] : bfu2f(((const unsigned short*)p)[i]);
}
__device__ __forceinline__ int load_idx(const void* ei, size_t i, int i64) {
    return i64 ? (int)((const long long*)ei)[i] : ((const int*)ei)[i];
}

// ---- runtime dtype detection (R8 counters confirmed fp32+int32) -----------
__global__ __launch_bounds__(256) void k_detect(
    const uint4* __restrict__ x4, const int* __restrict__ ei32,
    int* __restrict__ flags)
{
    __shared__ int cff, cnz;
    int t = threadIdx.x;
    if (t == 0) { cff = 0; cnz = 0; }
    __syncthreads();
    int lff = 0;
    #pragma unroll
    for (int j = 0; j < 16; ++j) {               // 16384 dwords of x
        uint4 w = x4[t + j * 256];
        unsigned int a[4] = {w.x, w.y, w.z, w.w};
        #pragma unroll
        for (int q = 0; q < 4; ++q) {
            // fp32 data: low mantissa half as pseudo-bf16 exponent hits 0xFF
            // w.p. 1/256 per dword; bf16 pairs never have exp==0xFF (no inf/NaN)
            if ((a[q] & 0x00007F80u) == 0x00007F80u) lff++;
            if ((a[q] & 0x7F800000u) == 0x7F800000u) lff++;
        }
    }
    int lnz = 0;
    for (int i = t; i < 2048; i += 256)
        if (ei32[2 * i + 1] != 0) lnz++;
    if (lff) atomicAdd(&cff, lff);
    if (lnz) atomicAdd(&cnz, lnz);
    __syncthreads();
    if (t == 0) {
        flags[0] = (cff > 0) ? 1 : 0;   // 1 = fp32 floats (confirmed on HW)
        flags[1] = (cnz == 0) ? 1 : 0;  // 1 = int64 indices (HW: int32)
    }
}

// ---- CSR pass A: degree count + within-segment position (ONE atomic/edge) -
// cnt padded to one counter per 64-B line (R4; kept — cheap insurance)
__global__ __launch_bounds__(256) void k_hist(
    const void* __restrict__ ei, const int* __restrict__ flags,
    int* __restrict__ cnt, unsigned short* __restrict__ pos)
{
    int e = blockIdx.x * 256 + threadIdx.x;
    int d = load_idx(ei, (size_t)N_EDGES + e, flags[1]);
    pos[e] = (unsigned short)atomicAdd(&cnt[d << 4], 1);
}

// ---- CSR pass B1: per-block sums of cnt (strided by 16) -------------------
__global__ __launch_bounds__(256) void k_scan1(
    const int* __restrict__ cnt, int* __restrict__ bsum)
{
    __shared__ int red[256];
    int t = threadIdx.x, b = blockIdx.x;
    int base = b * 4096;
    int s = 0;
    #pragma unroll
    for (int j = 0; j < 16; ++j) {
        int i = base + j * 256 + t;
        if (i < N_NODES) s += cnt[i << 4];
    }
    red[t] = s;
    #pragma unroll
    for (int off = 128; off > 0; off >>= 1) {
        __syncthreads();
        if (t < off) red[t] += red[t + off];
    }
    if (t == 0) bsum[b] = red[0];
}

// ---- CSR pass B2: per-block exclusive scan -> row_ptr ---------------------
__global__ __launch_bounds__(256) void k_scan3(
    const int* __restrict__ cnt, const int* __restrict__ bsum,
    int* __restrict__ row_ptr)
{
    __shared__ int tsum[256];
    __shared__ int off_sh;
    int t = threadIdx.x, b = blockIdx.x;
    if (t == 0) {
        int o = 0;
        for (int i = 0; i < b; ++i) o += bsum[i];
        off_sh = o;
        if (b == 0) row_ptr[N_NODES] = N_EDGES;   // total is a constant
    }
    int base = b * 4096 + t * 16;
    int v[16], s = 0;
    #pragma unroll
    for (int j = 0; j < 16; ++j) {
        int i = base + j;
        v[j] = (i < N_NODES) ? cnt[i << 4] : 0;
        s += v[j];
    }
    tsum[t] = s;
    #pragma unroll
    for (int off = 1; off < 256; off <<= 1) {
        __syncthreads();
        int val = (t >= off) ? tsum[t - off] : 0;
        __syncthreads();
        tsum[t] += val;
    }
    __syncthreads();
    int run = off_sh + (t ? tsum[t - 1] : 0);
    #pragma unroll
    for (int j = 0; j < 16; ++j) {
        int i = base + j;
        if (i < N_NODES) { row_ptr[i] = run; run += v[j]; }
    }
}

// ---- CSR pass C: scatter packed {dst&7 : 3 | src : 17 | wq : 12} ----------
// dst&7 gives the wave-local accumulator slot in k_msg_sl (dst groups are
// 8-aligned). 12-bit w: rel err 2.4e-4. NO atomics here.
__global__ __launch_bounds__(256) void k_scatter(
    const void* __restrict__ ea, const void* __restrict__ ei,
    const int* __restrict__ flags, const int* __restrict__ row_ptr,
    const unsigned short* __restrict__ pos, unsigned int* __restrict__ srt)
{
    int e = blockIdx.x * 256 + threadIdx.x;
    int s = load_idx(ei, (size_t)e, flags[1]);
    int d = load_idx(ei, (size_t)N_EDGES + e, flags[1]);
    float w = expf(load_f(ea, e, flags[0]));     // unnormalized, in [1, e)
    unsigned int wb = __float_as_uint(w);
    int wq = (int)((wb + 0x800u) >> 12) - 0x3F800;   // round-to-nearest
    wq = wq < 0 ? 0 : (wq > 0xFFF ? 0xFFF : wq);     // clamp (out-of-dist ea)
    int p = row_ptr[d] + pos[e];
    unsigned int pk = ((unsigned int)(d & 7) << 29) | ((unsigned int)s << 12)
                    | (unsigned int)wq;
    __builtin_nontemporal_store(pk, srt + p);
}

// ---- GEMM1: xw[n,c] = sum_k x[n,k] * W1[c,k]; OUTPUT bf16, SLABBED --------
// slab s holds channels 16s..16s+15 for all nodes: 3.2 MB contiguous.
#define W1_STRIDE (IN_C + 4)   // 132
__global__ __launch_bounds__(256) void k_gemm1(
    const void* __restrict__ x, const void* __restrict__ W,
    const int* __restrict__ flags, unsigned short* __restrict__ xw)
{
    __shared__ float Wls[C * W1_STRIDE];
    __shared__ float xs[32 * IN_C];
    int t = threadIdx.x;
    int f32 = flags[0];
    size_t xbase = (size_t)blockIdx.x * 32 * IN_C;
    if (f32) {
        const float* xp = (const float*)x + xbase;
        #pragma unroll
        for (int j = 0; j < 16; ++j) { int i = t + j * 256; xs[i] = xp[i]; }
        const float* wp = (const float*)W;
        #pragma unroll
        for (int j = 0; j < 32; ++j) {
            int i = t + j * 256;
            Wls[(i >> 7) * W1_STRIDE + (i & 127)] = wp[i];
        }
    } else {
        const unsigned int* xp = (const unsigned int*)((const unsigned short*)x + xbase);
        #pragma unroll
        for (int j = 0; j < 8; ++j) {
            int i = t + j * 256;
            unsigned int v = xp[i];
            xs[2 * i]     = blo(v);
            xs[2 * i + 1] = bhi(v);
        }
        const unsigned short* wp = (const unsigned short*)W;
        #pragma unroll
        for (int j = 0; j < 32; ++j) {
            int i = t + j * 256;
            Wls[(i >> 7) * W1_STRIDE + (i & 127)] = bfu2f(wp[i]);
        }
    }
    __syncthreads();
    int col = t & 63, wv = t >> 6;
    const float* wr = Wls + col * W1_STRIDE;
    const float* xr = xs + wv * 8 * IN_C;
    float acc[8];
    #pragma unroll
    for (int n = 0; n < 8; ++n) acc[n] = 0.f;
    #pragma unroll
    for (int kk = 0; kk < IN_C / 4; ++kk) {
        float4 w4 = *(const float4*)(wr + kk * 4);
        #pragma unroll
        for (int n = 0; n < 8; ++n) {
            float4 x4 = *(const float4*)(xr + n * IN_C + kk * 4);
            acc[n] += x4.x * w4.x + x4.y * w4.y + x4.z * w4.z + x4.w * w4.w;
        }
    }
    int sl = col >> 4, cc = col & 15;
    size_t sb = (size_t)sl * (N_NODES * 16);
    int r0 = blockIdx.x * 32 + wv * 8;
    #pragma unroll
    for (int n = 0; n < 8; ++n)
        xw[sb + (size_t)(r0 + n) * 16 + cc] = f2bfu(acc[n]);
}

// ---- GEMM2: h (slabbed bf16) @ W2 -> xw (slabbed bf16) --------------------
#define W2_STRIDE (C + 4)      // 68
__global__ __launch_bounds__(256) void k_gemm2(
    const unsigned int* __restrict__ h, const void* __restrict__ W,
    const int* __restrict__ flags, unsigned short* __restrict__ xw)
{
    __shared__ float Wls[C * W2_STRIDE];
    __shared__ float xs[32 * C];
    int t = threadIdx.x;
    int rowbase = blockIdx.x * 32;
    #pragma unroll
    for (int j = 0; j < 4; ++j) {
        int i = t + j * 256;                      // 0..1023
        int row = i >> 5, dw = i & 31;            // dw = channel pair 2dw,2dw+1
        int sl = dw >> 3, dwp = dw & 7;
        unsigned int v = h[(size_t)sl * (N_NODES * 8) + (size_t)(rowbase + row) * 8 + dwp];
        xs[row * C + 2 * dw]     = blo(v);
        xs[row * C + 2 * dw + 1] = bhi(v);
    }
    if (flags[0]) {
        const float* wp = (const float*)W;
        #pragma unroll
        for (int j = 0; j < 16; ++j) {
            int i = t + j * 256;
            Wls[(i >> 6) * W2_STRIDE + (i & 63)] = wp[i];
        }
    } else {
        const unsigned short* wp = (const unsigned short*)W;
        #pragma unroll
        for (int j = 0; j < 16; ++j) {
            int i = t + j * 256;
            Wls[(i >> 6) * W2_STRIDE + (i & 63)] = bfu2f(wp[i]);
        }
    }
    __syncthreads();
    int col = t & 63, wv = t >> 6;
    const float* wr = Wls + col * W2_STRIDE;
    const float* xr = xs + wv * 8 * C;
    float acc[8];
    #pragma unroll
    for (int n = 0; n < 8; ++n) acc[n] = 0.f;
    #pragma unroll
    for (int kk = 0; kk < C / 4; ++kk) {
        float4 w4 = *(const float4*)(wr + kk * 4);
        #pragma unroll
        for (int n = 0; n < 8; ++n) {
            float4 x4 = *(const float4*)(xr + n * C + kk * 4);
            acc[n] += x4.x * w4.x + x4.y * w4.y + x4.z * w4.z + x4.w * w4.w;
        }
    }
    int sl = col >> 4, cc = col & 15;
    size_t sb = (size_t)sl * (N_NODES * 16);
    int r0 = blockIdx.x * 32 + wv * 8;
    #pragma unroll
    for (int n = 0; n < 8; ++n)
        xw[sb + (size_t)(r0 + n) * 16 + cc] = f2bfu(acc[n]);
}

// ---- sliced fused msg+update: flat-edge, LDS-atomic segmented reduce ------
// Wave owns 8 consecutive dsts -> ONE contiguous CSR edge range S (~128+-11):
//   * srt reads: coalesced 32-B segments, 2-deep register prefetch
//   * perfect balance: pad waste (8*ceil(S/8)-S)/S ~ 3% (was ~55% max-of-8)
//   * gathers independent across iterations -> deep ILP
//   * accumulate via ds_add_f32 into per-wave LDS (dst slot = p>>29); no
//     shuffles; all-64-lane coalesced epilogue write.
__global__ __launch_bounds__(256) void k_msg_sl(
    const unsigned int* __restrict__ xw_all,
    const unsigned int* __restrict__ srt,
    const int* __restrict__ row_ptr, const void* __restrict__ b,
    const int* __restrict__ flags, void* __restrict__ outp, int out_is_final)
{
    __shared__ float acc[4][192];      // per wave: 8 dst x 24 (16 ch + asum@16)
    int sl = blockIdx.x / MSG_NB;
    int bxi = blockIdx.x - sl * MSG_NB;
    const unsigned int* xw = xw_all + (size_t)sl * (N_NODES * 8);
    int wv = threadIdx.x >> 6, lane = threadIdx.x & 63;
    int g = lane >> 3, li = lane & 7;
    float* ac = acc[wv];
    #pragma unroll
    for (int i = 0; i < 3; ++i) ac[lane + i * 64] = 0.f;   // 192 = 3*64

    int dbase = bxi * 32 + wv * 8;
    int rp0 = row_ptr[dbase], rp8 = row_ptr[dbase + 8];
    int S = rp8 - rp0;
    int nit = (S + 7) >> 3;
    int idx = rp0 + g;
    int ci = idx < N_EDGES ? idx : N_EDGES - 1;
    unsigned int p = __builtin_nontemporal_load(srt + ci);
    int slot = g;
    for (int it = 0; it < nit; ++it) {           // uniform trip: no divergence
        int i2 = idx + 8;
        int c2 = i2 < N_EDGES ? i2 : N_EDGES - 1;
        unsigned int pn = __builtin_nontemporal_load(srt + c2);   // prefetch
        float w = (slot < S) ? dec_w12(p) : 0.f;
        int dl = p >> 29;
        unsigned int v = xw[(size_t)((p >> 12) & 0x1FFFFu) * 8 + li];
        float* a0 = ac + dl * 24 + li * 2;
        atomicAdd(a0,     w * blo(v));
        atomicAdd(a0 + 1, w * bhi(v));
        if (li == 0) atomicAdd(ac + dl * 24 + 16, w);
        p = pn; idx = i2; slot += 8;
    }
    // only this wave touches its acc region; same-wave DS ops are ordered
    float sx = ac[g * 24 + li * 2];
    float sy = ac[g * 24 + li * 2 + 1];
    float as = ac[g * 24 + 16];
    float inv = (as > 0.5f) ? 1.f / as : 0.f;    // w>=1 per edge; 0 iff deg==0
    int d = dbase + g;
    unsigned int sv = xw[(size_t)d * 8 + li];    // self row (slab-resident)
    int f32 = flags[0];
    float b0, b1;
    if (f32) {
        vfloat2 bb = ((const vfloat2*)b)[sl * 8 + li];
        b0 = bb.x; b1 = bb.y;
    } else {
        unsigned int bb = ((const unsigned int*)b)[sl * 8 + li];
        b0 = blo(bb); b1 = bhi(bb);
    }
    float r0 = 1.f / (1.f + expf(-(sx * inv + blo(sv) + b0)));
    float r1 = 1.f / (1.f + expf(-(sy * inv + bhi(sv) + b1)));
    if (out_is_final) {
        if (f32) {
            vfloat2 rv; rv.x = r0; rv.y = r1;
            __builtin_nontemporal_store(rv, (vfloat2*)outp + (size_t)d * 32 + sl * 8 + li);
        } else {
            unsigned int packed = (unsigned int)f2bfu(r0) | ((unsigned int)f2bfu(r1) << 16);
            __builtin_nontemporal_store(packed, (unsigned int*)outp + (size_t)d * 32 + sl * 8 + li);
        }
    } else {
        // intermediate h1, slabbed layout (matches gemm2 reader)
        unsigned int packed = (unsigned int)f2bfu(r0) | ((unsigned int)f2bfu(r1) << 16);
        __builtin_nontemporal_store(packed,
            (unsigned int*)outp + (size_t)sl * (N_NODES * 8) + (size_t)d * 8 + li);
    }
}

extern "C" void kernel_launch(void* const* d_in, const int* in_sizes, int n_in,
                              void* d_out, int out_size, void* d_ws, size_t ws_size,
                              hipStream_t stream) {
    const void* x  = d_in[0];
    const void* ei = d_in[1];
    const void* ea = d_in[2];
    const void* W1 = d_in[3];
    const void* b1 = d_in[4];
    const void* W2 = d_in[5];
    const void* b2 = d_in[6];

    char* base = (char*)d_ws;
    int*            flags   = (int*)base;                  // 256 B
    int*            cnt     = (int*)(base + 256);          // 100K counters @ 64B stride = 6.4 MB
    int*            row_ptr = (int*)(base + 6400256);      // N+1 (+pad)
    unsigned short* pos     = (unsigned short*)(base + 6800272);   // E (2B)
    int*            bsum    = (int*)(base + 10000272);     // 25 (+pad)
    unsigned int*   srt     = (unsigned int*)(base + 10000528);    // E (4B packed)
    unsigned short* xw      = (unsigned short*)(base + 16400528);  // 4 slabs x N*16 bf16
    unsigned short* h1      = (unsigned short*)(base + 29200528);  // 4 slabs x N*16 bf16
    // total ws use ≈ 42.0 MB

    k_detect<<<1, 256, 0, stream>>>((const uint4*)x, (const int*)ei, flags);
    hipMemsetAsync(cnt, 0, 6400000, stream);

    // CSR build: count+pos (1 atomic/edge, line-padded), scan, packed scatter
    k_hist<<<N_EDGES / 256, 256, 0, stream>>>(ei, flags, cnt, pos);
    k_scan1<<<SCAN_NB, 256, 0, stream>>>(cnt, bsum);
    k_scan3<<<SCAN_NB, 256, 0, stream>>>(cnt, bsum, row_ptr);
    k_scatter<<<N_EDGES / 256, 256, 0, stream>>>(ea, ei, flags, row_ptr, pos, srt);

    // layer 1: gemm then one fused 4-slab msg launch
    k_gemm1<<<N_NODES / 32, 256, 0, stream>>>(x, W1, flags, xw);
    k_msg_sl<<<MSG_NB * NSLAB, 256, 0, stream>>>(
        (const unsigned int*)xw, srt, row_ptr, b1, flags, h1, 0);

    // layer 2
    k_gemm2<<<N_NODES / 32, 256, 0, stream>>>((const unsigned int*)h1, W2, flags, xw);
    k_msg_sl<<<MSG_NB * NSLAB, 256, 0, stream>>>(
        (const unsigned int*)xw, srt, row_ptr, b2, flags, d_out, 1);
}

// Round 6
// 423.107 us; speedup vs baseline: 3.3927x; 3.3927x over previous
//
#include <hip/hip_runtime.h>
#include <hip/hip_bf16.h>

#define N_NODES 100000
#define N_EDGES 1600000
#define IN_C 128
#define C 64            // hid_c == out_c
#define SCAN_NB 25      // ceil(N_NODES / 4096)

typedef float vfloat2 __attribute__((ext_vector_type(2)));

__device__ __forceinline__ float bfu2f(unsigned short u) {
    return __uint_as_float(((unsigned int)u) << 16);
}
__device__ __forceinline__ unsigned short f2bfu(float f) {
    __hip_bfloat16 h = __float2bfloat16(f);
    unsigned short u; __builtin_memcpy(&u, &h, 2); return u;
}
// bf16x2 unpack, 1 VALU op each
__device__ __forceinline__ float blo(unsigned int v) { return __uint_as_float(v << 16); }
__device__ __forceinline__ float bhi(unsigned int v) { return __uint_as_float(v & 0xFFFF0000u); }
// 15-bit weight decode: w in [1, ~3.42), rel err ~3e-5
__device__ __forceinline__ float dec_w(unsigned int p) {
    return __uint_as_float(((p & 0x7FFFu) + 0x1FC000u) << 9);
}
__device__ __forceinline__ float load_f(const void* p, int i, int f32) {
    return f32 ? ((const float*)p)[i] : bfu2f(((const unsigned short*)p)[i]);
}
__device__ __forceinline__ int load_idx(const void* ei, size_t i, int i64) {
    return i64 ? (int)((const long long*)ei)[i] : ((const int*)ei)[i];
}

// ---- runtime dtype detection (counters confirmed fp32+int32) --------------
__global__ __launch_bounds__(256) void k_detect(
    const uint4* __restrict__ x4, const int* __restrict__ ei32,
    int* __restrict__ flags)
{
    __shared__ int cff, cnz;
    int t = threadIdx.x;
    if (t == 0) { cff = 0; cnz = 0; }
    __syncthreads();
    int lff = 0;
    #pragma unroll
    for (int j = 0; j < 16; ++j) {               // 16384 dwords of x
        uint4 w = x4[t + j * 256];
        unsigned int a[4] = {w.x, w.y, w.z, w.w};
        #pragma unroll
        for (int q = 0; q < 4; ++q) {
            // fp32 data: low mantissa half as pseudo-bf16 exponent hits 0xFF
            // w.p. 1/256 per dword; bf16 pairs never have exp==0xFF (no inf/NaN)
            if ((a[q] & 0x00007F80u) == 0x00007F80u) lff++;
            if ((a[q] & 0x7F800000u) == 0x7F800000u) lff++;
        }
    }
    int lnz = 0;
    for (int i = t; i < 2048; i += 256)
        if (ei32[2 * i + 1] != 0) lnz++;
    if (lff) atomicAdd(&cff, lff);
    if (lnz) atomicAdd(&cnz, lnz);
    __syncthreads();
    if (t == 0) {
        flags[0] = (cff > 0) ? 1 : 0;   // 1 = fp32 floats (confirmed on HW)
        flags[1] = (cnz == 0) ? 1 : 0;  // 1 = int64 indices (HW: int32)
    }
}

// ---- CSR pass A: degree count + within-segment position (ONE atomic/edge) -
// 24 G-atomics/s device-scope op-rate ceiling (R3-R5: padding doesn't help).
__global__ __launch_bounds__(256) void k_hist(
    const void* __restrict__ ei, const int* __restrict__ flags,
    int* __restrict__ cnt, unsigned short* __restrict__ pos)
{
    int e = blockIdx.x * 256 + threadIdx.x;
    int d = load_idx(ei, (size_t)N_EDGES + e, flags[1]);
    pos[e] = (unsigned short)atomicAdd(&cnt[d], 1);
}

// ---- CSR pass B1: per-block sums of cnt (coalesced) -----------------------
__global__ __launch_bounds__(256) void k_scan1(
    const int* __restrict__ cnt, int* __restrict__ bsum)
{
    __shared__ int red[256];
    int t = threadIdx.x, b = blockIdx.x;
    int base = b * 4096;
    int s = 0;
    #pragma unroll
    for (int j = 0; j < 16; ++j) {
        int i = base + j * 256 + t;
        if (i < N_NODES) s += cnt[i];
    }
    red[t] = s;
    #pragma unroll
    for (int off = 128; off > 0; off >>= 1) {
        __syncthreads();
        if (t < off) red[t] += red[t + off];
    }
    if (t == 0) bsum[b] = red[0];
}

// ---- CSR pass B2: per-block exclusive scan -> row_ptr ---------------------
__global__ __launch_bounds__(256) void k_scan3(
    const int* __restrict__ cnt, const int* __restrict__ bsum,
    int* __restrict__ row_ptr)
{
    __shared__ int tsum[256];
    __shared__ int off_sh;
    int t = threadIdx.x, b = blockIdx.x;
    if (t == 0) {
        int o = 0;
        for (int i = 0; i < b; ++i) o += bsum[i];
        off_sh = o;
        if (b == 0) row_ptr[N_NODES] = N_EDGES;   // total is a constant
    }
    int base = b * 4096 + t * 16;
    int v[16], s = 0;
    #pragma unroll
    for (int j = 0; j < 16; ++j) {
        int i = base + j;
        v[j] = (i < N_NODES) ? cnt[i] : 0;
        s += v[j];
    }
    tsum[t] = s;
    #pragma unroll
    for (int off = 1; off < 256; off <<= 1) {
        __syncthreads();
        int val = (t >= off) ? tsum[t - off] : 0;
        __syncthreads();
        tsum[t] += val;
    }
    __syncthreads();
    int run = off_sh + (t ? tsum[t - 1] : 0);
    #pragma unroll
    for (int j = 0; j < 16; ++j) {
        int i = base + j;
        if (i < N_NODES) { row_ptr[i] = run; run += v[j]; }
    }
}

// ---- CSR pass C: scatter packed {src[17b] | wq[15b]} — NO atomics ---------
// w = exp(ea) in [1, e) for ea ~ U[0,1): 15 bits of float-bit space covers
// [1.0, ~3.42) at rel err ~3e-5. 4B/edge halves the random-scatter traffic.
__global__ __launch_bounds__(256) void k_scatter(
    const void* __restrict__ ea, const void* __restrict__ ei,
    const int* __restrict__ flags, const int* __restrict__ row_ptr,
    const unsigned short* __restrict__ pos, unsigned int* __restrict__ srt)
{
    int e = blockIdx.x * 256 + threadIdx.x;
    int s = load_idx(ei, (size_t)e, flags[1]);
    int d = load_idx(ei, (size_t)N_EDGES + e, flags[1]);
    float w = expf(load_f(ea, e, flags[0]));     // unnormalized
    unsigned int wb = __float_as_uint(w);
    int wq = (int)((wb + 0x100u) >> 9) - 0x1FC000;   // round-to-nearest
    wq = wq < 0 ? 0 : (wq > 0x7FFF ? 0x7FFF : wq);   // clamp (out-of-dist ea)
    int p = row_ptr[d] + pos[e];
    __builtin_nontemporal_store(((unsigned int)s << 15) | (unsigned int)wq, srt + p);
}

// ---- GEMM1: xw[n,c] = sum_k x[n,k] * W1[c,k]; OUTPUT ALWAYS bf16 ----------
#define W1_STRIDE (IN_C + 4)   // 132
__global__ __launch_bounds__(256) void k_gemm1(
    const void* __restrict__ x, const void* __restrict__ W,
    const int* __restrict__ flags, unsigned short* __restrict__ xw)
{
    __shared__ float Wls[C * W1_STRIDE];
    __shared__ float xs[32 * IN_C];
    int t = threadIdx.x;
    int f32 = flags[0];
    size_t xbase = (size_t)blockIdx.x * 32 * IN_C;
    if (f32) {
        const float* xp = (const float*)x + xbase;
        #pragma unroll
        for (int j = 0; j < 16; ++j) { int i = t + j * 256; xs[i] = xp[i]; }
        const float* wp = (const float*)W;
        #pragma unroll
        for (int j = 0; j < 32; ++j) {
            int i = t + j * 256;
            Wls[(i >> 7) * W1_STRIDE + (i & 127)] = wp[i];
        }
    } else {
        const unsigned int* xp = (const unsigned int*)((const unsigned short*)x + xbase);
        #pragma unroll
        for (int j = 0; j < 8; ++j) {
            int i = t + j * 256;
            unsigned int v = xp[i];
            xs[2 * i]     = blo(v);
            xs[2 * i + 1] = bhi(v);
        }
        const unsigned short* wp = (const unsigned short*)W;
        #pragma unroll
        for (int j = 0; j < 32; ++j) {
            int i = t + j * 256;
            Wls[(i >> 7) * W1_STRIDE + (i & 127)] = bfu2f(wp[i]);
        }
    }
    __syncthreads();
    int col = t & 63, wv = t >> 6;
    const float* wr = Wls + col * W1_STRIDE;
    const float* xr = xs + wv * 8 * IN_C;
    float acc[8];
    #pragma unroll
    for (int n = 0; n < 8; ++n) acc[n] = 0.f;
    #pragma unroll
    for (int kk = 0; kk < IN_C / 4; ++kk) {
        float4 w4 = *(const float4*)(wr + kk * 4);
        #pragma unroll
        for (int n = 0; n < 8; ++n) {
            float4 x4 = *(const float4*)(xr + n * IN_C + kk * 4);
            acc[n] += x4.x * w4.x + x4.y * w4.y + x4.z * w4.z + x4.w * w4.w;
        }
    }
    size_t obase = (size_t)blockIdx.x * 32 * C + wv * 8 * C + col;
    #pragma unroll
    for (int n = 0; n < 8; ++n) xw[obase + n * C] = f2bfu(acc[n]);
}

// ---- GEMM2: h (bf16 internal) @ W2 -> xw (bf16 internal) ------------------
#define W2_STRIDE (C + 4)      // 68
__global__ __launch_bounds__(256) void k_gemm2(
    const unsigned int* __restrict__ h, const void* __restrict__ W,
    const int* __restrict__ flags, unsigned short* __restrict__ xw)
{
    __shared__ float Wls[C * W2_STRIDE];
    __shared__ float xs[32 * C];
    int t = threadIdx.x;
    size_t dwbase = (size_t)blockIdx.x * 32 * 32;   // 32 rows x 32 dwords
    #pragma unroll
    for (int j = 0; j < 4; ++j) {
        int i = t + j * 256;
        unsigned int v = h[dwbase + i];
        xs[2 * i]     = blo(v);
        xs[2 * i + 1] = bhi(v);
    }
    if (flags[0]) {
        const float* wp = (const float*)W;
        #pragma unroll
        for (int j = 0; j < 16; ++j) {
            int i = t + j * 256;
            Wls[(i >> 6) * W2_STRIDE + (i & 63)] = wp[i];
        }
    } else {
        const unsigned short* wp = (const unsigned short*)W;
        #pragma unroll
        for (int j = 0; j < 16; ++j) {
            int i = t + j * 256;
            Wls[(i >> 6) * W2_STRIDE + (i & 63)] = bfu2f(wp[i]);
        }
    }
    __syncthreads();
    int col = t & 63, wv = t >> 6;
    const float* wr = Wls + col * W2_STRIDE;
    const float* xr = xs + wv * 8 * C;
    float acc[8];
    #pragma unroll
    for (int n = 0; n < 8; ++n) acc[n] = 0.f;
    #pragma unroll
    for (int kk = 0; kk < C / 4; ++kk) {
        float4 w4 = *(const float4*)(wr + kk * 4);
        #pragma unroll
        for (int n = 0; n < 8; ++n) {
            float4 x4 = *(const float4*)(xr + n * C + kk * 4);
            acc[n] += x4.x * w4.x + x4.y * w4.y + x4.z * w4.z + x4.w * w4.w;
        }
    }
    size_t obase = (size_t)blockIdx.x * 32 * C + wv * 8 * C + col;
    #pragma unroll
    for (int n = 0; n < 8; ++n) xw[obase + n * C] = f2bfu(acc[n]);
}

// ---- fused msg+update: wave per dst (R1 shape — best measured: 67.9 us) ---
// out = sigmoid( (Σ exp_e·xw[src_e]) / (Σ exp_e) + xw[d] + b )
// half-wave h owns edges [j+4h, j+4h+3]: 4 contiguous srt dwords (coalesced),
// 8 gather instructions in flight per wave. srt is 4B packed {src|w}.
__global__ __launch_bounds__(256) void k_msg_csr(
    const unsigned int* __restrict__ xw, const unsigned int* __restrict__ srt,
    const int* __restrict__ row_ptr, const void* __restrict__ b,
    const int* __restrict__ flags, void* __restrict__ outp, int out_is_final)
{
    int d = blockIdx.x * 4 + (threadIdx.x >> 6);
    int lane = threadIdx.x & 63;
    int half = lane >> 5, li = lane & 31;
    int beg = row_ptr[d], end = row_ptr[d + 1];
    float accx = 0.f, accy = 0.f, asum = 0.f;
    int j = beg;
    for (; j + 8 <= end; j += 8) {
        int jb = j + 4 * half;
        unsigned int p0 = __builtin_nontemporal_load(srt + jb);
        unsigned int p1 = __builtin_nontemporal_load(srt + jb + 1);
        unsigned int p2 = __builtin_nontemporal_load(srt + jb + 2);
        unsigned int p3 = __builtin_nontemporal_load(srt + jb + 3);
        unsigned int v0 = xw[(size_t)(p0 >> 15) * 32 + li];
        unsigned int v1 = xw[(size_t)(p1 >> 15) * 32 + li];
        unsigned int v2 = xw[(size_t)(p2 >> 15) * 32 + li];
        unsigned int v3 = xw[(size_t)(p3 >> 15) * 32 + li];
        float w0 = dec_w(p0), w1 = dec_w(p1), w2 = dec_w(p2), w3 = dec_w(p3);
        accx += w0 * blo(v0) + w1 * blo(v1) + w2 * blo(v2) + w3 * blo(v3);
        accy += w0 * bhi(v0) + w1 * bhi(v1) + w2 * bhi(v2) + w3 * bhi(v3);
        asum += (w0 + w1) + (w2 + w3);
    }
    if (j + 4 <= end) {                       // straight-line tails: 4, 2, 1
        int jb = j + 2 * half;
        unsigned int p0 = __builtin_nontemporal_load(srt + jb);
        unsigned int p1 = __builtin_nontemporal_load(srt + jb + 1);
        unsigned int v0 = xw[(size_t)(p0 >> 15) * 32 + li];
        unsigned int v1 = xw[(size_t)(p1 >> 15) * 32 + li];
        float w0 = dec_w(p0), w1 = dec_w(p1);
        accx += w0 * blo(v0) + w1 * blo(v1);
        accy += w0 * bhi(v0) + w1 * bhi(v1);
        asum += w0 + w1;
        j += 4;
    }
    if (j + 2 <= end) {
        unsigned int p0 = __builtin_nontemporal_load(srt + j + half);
        unsigned int v0 = xw[(size_t)(p0 >> 15) * 32 + li];
        float w0 = dec_w(p0);
        accx += w0 * blo(v0);
        accy += w0 * bhi(v0);
        asum += w0;
        j += 2;
    }
    if (j < end && half == 0) {
        unsigned int p0 = __builtin_nontemporal_load(srt + j);
        unsigned int v0 = xw[(size_t)(p0 >> 15) * 32 + li];
        float w0 = dec_w(p0);
        accx += w0 * blo(v0);
        accy += w0 * bhi(v0);
        asum += w0;
    }
    accx += __shfl_xor(accx, 32);
    accy += __shfl_xor(accy, 32);
    asum += __shfl_xor(asum, 32);
    float inv = (end > beg) ? 1.f / asum : 0.f;
    unsigned int sv = xw[(size_t)d * 32 + li];
    int f32 = flags[0];
    float b0 = load_f(b, 2 * li, f32), b1 = load_f(b, 2 * li + 1, f32);
    float v0 = accx * inv + blo(sv) + b0;
    float v1 = accy * inv + bhi(sv) + b1;
    float r0 = 1.f / (1.f + expf(-v0));
    float r1 = 1.f / (1.f + expf(-v1));
    if (half == 0) {
        if (out_is_final && f32) {
            vfloat2 rv; rv.x = r0; rv.y = r1;
            __builtin_nontemporal_store(rv, (vfloat2*)outp + (size_t)d * 32 + li);
        } else {
            unsigned int packed = (unsigned int)f2bfu(r0) | ((unsigned int)f2bfu(r1) << 16);
            __builtin_nontemporal_store(packed, (unsigned int*)outp + (size_t)d * 32 + li);
        }
    }
}

extern "C" void kernel_launch(void* const* d_in, const int* in_sizes, int n_in,
                              void* d_out, int out_size, void* d_ws, size_t ws_size,
                              hipStream_t stream) {
    const void* x  = d_in[0];
    const void* ei = d_in[1];
    const void* ea = d_in[2];
    const void* W1 = d_in[3];
    const void* b1 = d_in[4];
    const void* W2 = d_in[5];
    const void* b2 = d_in[6];

    char* base = (char*)d_ws;
    int*            flags   = (int*)base;                 // 256 B
    int*            cnt     = (int*)(base + 256);         // N
    int*            row_ptr = (int*)(base + 400256);      // N+1 (+pad)
    unsigned short* pos     = (unsigned short*)(base + 800272);  // E (2B)
    int*            bsum    = (int*)(base + 4000272);     // 25 (+pad)
    unsigned int*   srt     = (unsigned int*)(base + 4000528);   // E (4B packed)
    unsigned short* xw      = (unsigned short*)(base + 10400576); // N*64 bf16
    unsigned short* h1      = (unsigned short*)(base + 23200576); // N*64 bf16
    // total ws use ≈ 36.0 MB

    k_detect<<<1, 256, 0, stream>>>((const uint4*)x, (const int*)ei, flags);
    hipMemsetAsync(cnt, 0, 400000, stream);

    // CSR build: count+pos (1 atomic/edge), scan, atomic-free packed scatter
    k_hist<<<N_EDGES / 256, 256, 0, stream>>>(ei, flags, cnt, pos);
    k_scan1<<<SCAN_NB, 256, 0, stream>>>(cnt, bsum);
    k_scan3<<<SCAN_NB, 256, 0, stream>>>(cnt, bsum, row_ptr);
    k_scatter<<<N_EDGES / 256, 256, 0, stream>>>(ea, ei, flags, row_ptr, pos, srt);

    // layer 1 (internal node features bf16)
    k_gemm1<<<N_NODES / 32, 256, 0, stream>>>(x, W1, flags, xw);
    k_msg_csr<<<N_NODES / 4, 256, 0, stream>>>((const unsigned int*)xw, srt, row_ptr, b1, flags, h1, 0);

    // layer 2
    k_gemm2<<<N_NODES / 32, 256, 0, stream>>>((const unsigned int*)h1, W2, flags, xw);
    k_msg_csr<<<N_NODES / 4, 256, 0, stream>>>((const unsigned int*)xw, srt, row_ptr, b2, flags, d_out, 1);
}

// Round 8
// 340.286 us; speedup vs baseline: 4.2185x; 1.2434x over previous
//
#include <hip/hip_runtime.h>
#include <hip/hip_bf16.h>

#define N_NODES 100000
#define N_EDGES 1600000
#define IN_C 128
#define C 64            // hid_c == out_c
#define NBKT 196        // coarse buckets: dst>>9 (512 dsts each)
#define CAP 9216        // bucket capacity: mean 8192, +11 sigma slack
#define BCHK 6400       // edges per k_bucket block (25/thread)
#define NBB (N_EDGES / BCHK)   // 250

typedef float vfloat2 __attribute__((ext_vector_type(2)));

__device__ __forceinline__ float bfu2f(unsigned short u) {
    return __uint_as_float(((unsigned int)u) << 16);
}
__device__ __forceinline__ unsigned short f2bfu(float f) {
    __hip_bfloat16 h = __float2bfloat16(f);
    unsigned short u; __builtin_memcpy(&u, &h, 2); return u;
}
// bf16x2 unpack, 1 VALU op each
__device__ __forceinline__ float blo(unsigned int v) { return __uint_as_float(v << 16); }
__device__ __forceinline__ float bhi(unsigned int v) { return __uint_as_float(v & 0xFFFF0000u); }
// 15-bit weight decode: w in [1, ~3.42), rel err ~3e-5
__device__ __forceinline__ float dec_w(unsigned int p) {
    return __uint_as_float(((p & 0x7FFFu) + 0x1FC000u) << 9);
}
__device__ __forceinline__ float load_f(const void* p, int i, int f32) {
    return f32 ? ((const float*)p)[i] : bfu2f(((const unsigned short*)p)[i]);
}
__device__ __forceinline__ int load_idx(const void* ei, size_t i, int i64) {
    return i64 ? (int)((const long long*)ei)[i] : ((const int*)ei)[i];
}

// ---- runtime dtype detection (counters confirmed fp32+int32) --------------
__global__ __launch_bounds__(256) void k_detect(
    const uint4* __restrict__ x4, const int* __restrict__ ei32,
    int* __restrict__ flags)
{
    __shared__ int cff, cnz;
    int t = threadIdx.x;
    if (t == 0) { cff = 0; cnz = 0; }
    __syncthreads();
    int lff = 0;
    #pragma unroll
    for (int j = 0; j < 16; ++j) {               // 16384 dwords of x
        uint4 w = x4[t + j * 256];
        unsigned int a[4] = {w.x, w.y, w.z, w.w};
        #pragma unroll
        for (int q = 0; q < 4; ++q) {
            // fp32 data: low mantissa half as pseudo-bf16 exponent hits 0xFF
            // w.p. 1/256 per dword; bf16 pairs never have exp==0xFF (no inf/NaN)
            if ((a[q] & 0x00007F80u) == 0x00007F80u) lff++;
            if ((a[q] & 0x7F800000u) == 0x7F800000u) lff++;
        }
    }
    int lnz = 0;
    for (int i = t; i < 2048; i += 256)
        if (ei32[2 * i + 1] != 0) lnz++;
    if (lff) atomicAdd(&cff, lff);
    if (lnz) atomicAdd(&cnz, lnz);
    __syncthreads();
    if (t == 0) {
        flags[0] = (cff > 0) ? 1 : 0;   // 1 = fp32 floats (confirmed on HW)
        flags[1] = (cnz == 0) ? 1 : 0;  // 1 = int64 indices (HW: int32)
    }
}

// ---- CSR build pass 1: coarse bucket (LDS hist + 196 global atomics) ------
// Replaces k_hist's 1.6M device atomics (67 us @ 24 Gops/s, 53 MB RMW
// write-through) with 1.6M cheap LDS int atomics (196 counters, low
// contention) + 49K global atomics total.
__global__ __launch_bounds__(256) void k_bucket(
    const void* __restrict__ ea, const void* __restrict__ ei,
    const int* __restrict__ flags, int* __restrict__ gcnt,
    int2* __restrict__ bkt)
{
    __shared__ int h[NBKT], lrk[NBKT], gbase[NBKT];
    int t = threadIdx.x;
    if (t < NBKT) { h[t] = 0; lrk[t] = 0; }
    __syncthreads();
    int i64 = flags[1], f32 = flags[0];
    int base = blockIdx.x * BCHK;
    for (int i = 0; i < 25; ++i) {
        int e = base + i * 256 + t;
        int d = load_idx(ei, (size_t)N_EDGES + e, i64);
        atomicAdd(&h[d >> 9], 1);
    }
    __syncthreads();
    if (t < NBKT) gbase[t] = atomicAdd(&gcnt[t], h[t]);
    __syncthreads();
    for (int i = 0; i < 25; ++i) {
        int e = base + i * 256 + t;
        int d = load_idx(ei, (size_t)N_EDGES + e, i64);
        int s = load_idx(ei, (size_t)e, i64);
        float w = expf(load_f(ea, e, f32));          // unnormalized, [1, e)
        unsigned int wb = __float_as_uint(w);
        int wq = (int)((wb + 0x100u) >> 9) - 0x1FC000;   // 15-bit round-nearest
        wq = wq < 0 ? 0 : (wq > 0x7FFF ? 0x7FFF : wq);
        int b = d >> 9;
        int lr = atomicAdd(&lrk[b], 1);              // block-local rank
        int idx = gbase[b] + lr;
        idx = idx < CAP ? idx : CAP - 1;             // fault insurance (+11 sigma)
        bkt[(size_t)b * CAP + idx] =
            make_int2((int)(((unsigned int)s << 15) | (unsigned int)wq), d);
    }
}

// ---- CSR build pass 1b: scan 196 bucket totals -> colbase -----------------
__global__ __launch_bounds__(256) void k_bktscan(
    const int* __restrict__ gcnt, int* __restrict__ colbase,
    int* __restrict__ row_ptr)
{
    __shared__ int ps[256];
    int t = threadIdx.x;
    int v = (t < NBKT) ? gcnt[t] : 0;
    ps[t] = v;
    for (int off = 1; off < 256; off <<= 1) {
        __syncthreads();
        int val = (t >= off) ? ps[t - off] : 0;
        __syncthreads();
        ps[t] += val;
    }
    __syncthreads();
    if (t < NBKT) colbase[t] = ps[t] - v;            // exclusive
    if (t == NBKT - 1) colbase[NBKT] = ps[t];        // == N_EDGES
    if (t == 0) row_ptr[N_NODES] = N_EDGES;
}

// ---- CSR build pass 2: per-bucket fine counting sort (L2-resident) --------
// Bucket data (~72 KB) is L2-hot from pass 1; final 4B-srt scatter lands in
// a ~36 KB L2-resident window — the random-write cost that made k_scatter
// slow is now absorbed by L2.
__global__ __launch_bounds__(256) void k_fine(
    const int2* __restrict__ bkt, const int* __restrict__ gcnt,
    const int* __restrict__ colbase, int* __restrict__ row_ptr,
    unsigned int* __restrict__ srt)
{
    __shared__ int h[512], ex[512], ps[256];
    int t = threadIdx.x, b = blockIdx.x;
    h[t] = 0; h[t + 256] = 0;
    __syncthreads();
    int nrec = gcnt[b];
    nrec = nrec < CAP ? nrec : CAP;                  // mirror of write clamp
    int cb = colbase[b];
    const int2* bp = bkt + (size_t)b * CAP;
    for (int i = t; i < nrec; i += 256)
        atomicAdd(&h[bp[i].y & 511], 1);
    __syncthreads();
    int s0 = h[2 * t], s1 = h[2 * t + 1];
    ps[t] = s0 + s1;
    for (int off = 1; off < 256; off <<= 1) {
        __syncthreads();
        int val = (t >= off) ? ps[t - off] : 0;
        __syncthreads();
        ps[t] += val;
    }
    __syncthreads();
    int pe = t ? ps[t - 1] : 0;
    ex[2 * t] = pe; ex[2 * t + 1] = pe + s0;
    __syncthreads();
    int d0 = b * 512 + t;
    if (d0 < N_NODES) row_ptr[d0] = cb + ex[t];
    int d1 = d0 + 256;
    if (d1 < N_NODES) row_ptr[d1] = cb + ex[t + 256];
    h[t] = 0; h[t + 256] = 0;                        // reuse h as rank counters
    __syncthreads();
    for (int i = t; i < nrec; i += 256) {
        int2 r = bp[i];
        int dl = r.y & 511;
        int rk = atomicAdd(&h[dl], 1);
        srt[cb + ex[dl] + rk] = (unsigned int)r.x;
    }
}

// ---- GEMM1: xw[n,c] = sum_k x[n,k] * W1[c,k]; OUTPUT ALWAYS bf16 ----------
#define W1_STRIDE (IN_C + 4)   // 132
__global__ __launch_bounds__(256) void k_gemm1(
    const void* __restrict__ x, const void* __restrict__ W,
    const int* __restrict__ flags, unsigned short* __restrict__ xw)
{
    __shared__ float Wls[C * W1_STRIDE];
    __shared__ float xs[32 * IN_C];
    int t = threadIdx.x;
    int f32 = flags[0];
    size_t xbase = (size_t)blockIdx.x * 32 * IN_C;
    if (f32) {
        const float* xp = (const float*)x + xbase;
        #pragma unroll
        for (int j = 0; j < 16; ++j) { int i = t + j * 256; xs[i] = xp[i]; }
        const float* wp = (const float*)W;
        #pragma unroll
        for (int j = 0; j < 32; ++j) {
            int i = t + j * 256;
            Wls[(i >> 7) * W1_STRIDE + (i & 127)] = wp[i];
        }
    } else {
        const unsigned int* xp = (const unsigned int*)((const unsigned short*)x + xbase);
        #pragma unroll
        for (int j = 0; j < 8; ++j) {
            int i = t + j * 256;
            unsigned int v = xp[i];
            xs[2 * i]     = blo(v);
            xs[2 * i + 1] = bhi(v);
        }
        const unsigned short* wp = (const unsigned short*)W;
        #pragma unroll
        for (int j = 0; j < 32; ++j) {
            int i = t + j * 256;
            Wls[(i >> 7) * W1_STRIDE + (i & 127)] = bfu2f(wp[i]);
        }
    }
    __syncthreads();
    int col = t & 63, wv = t >> 6;
    const float* wr = Wls + col * W1_STRIDE;
    const float* xr = xs + wv * 8 * IN_C;
    float acc[8];
    #pragma unroll
    for (int n = 0; n < 8; ++n) acc[n] = 0.f;
    #pragma unroll
    for (int kk = 0; kk < IN_C / 4; ++kk) {
        float4 w4 = *(const float4*)(wr + kk * 4);
        #pragma unroll
        for (int n = 0; n < 8; ++n) {
            float4 x4 = *(const float4*)(xr + n * IN_C + kk * 4);
            acc[n] += x4.x * w4.x + x4.y * w4.y + x4.z * w4.z + x4.w * w4.w;
        }
    }
    size_t obase = (size_t)blockIdx.x * 32 * C + wv * 8 * C + col;
    #pragma unroll
    for (int n = 0; n < 8; ++n) xw[obase + n * C] = f2bfu(acc[n]);
}

// ---- GEMM2: h (bf16 internal) @ W2 -> xw (bf16 internal) ------------------
#define W2_STRIDE (C + 4)      // 68
__global__ __launch_bounds__(256) void k_gemm2(
    const unsigned int* __restrict__ h, const void* __restrict__ W,
    const int* __restrict__ flags, unsigned short* __restrict__ xw)
{
    __shared__ float Wls[C * W2_STRIDE];
    __shared__ float xs[32 * C];
    int t = threadIdx.x;
    size_t dwbase = (size_t)blockIdx.x * 32 * 32;   // 32 rows x 32 dwords
    #pragma unroll
    for (int j = 0; j < 4; ++j) {
        int i = t + j * 256;
        unsigned int v = h[dwbase + i];
        xs[2 * i]     = blo(v);
        xs[2 * i + 1] = bhi(v);
    }
    if (flags[0]) {
        const float* wp = (const float*)W;
        #pragma unroll
        for (int j = 0; j < 16; ++j) {
            int i = t + j * 256;
            Wls[(i >> 6) * W2_STRIDE + (i & 63)] = wp[i];
        }
    } else {
        const unsigned short* wp = (const unsigned short*)W;
        #pragma unroll
        for (int j = 0; j < 16; ++j) {
            int i = t + j * 256;
            Wls[(i >> 6) * W2_STRIDE + (i & 63)] = bfu2f(wp[i]);
        }
    }
    __syncthreads();
    int col = t & 63, wv = t >> 6;
    const float* wr = Wls + col * W2_STRIDE;
    const float* xr = xs + wv * 8 * C;
    float acc[8];
    #pragma unroll
    for (int n = 0; n < 8; ++n) acc[n] = 0.f;
    #pragma unroll
    for (int kk = 0; kk < C / 4; ++kk) {
        float4 w4 = *(const float4*)(wr + kk * 4);
        #pragma unroll
        for (int n = 0; n < 8; ++n) {
            float4 x4 = *(const float4*)(xr + n * C + kk * 4);
            acc[n] += x4.x * w4.x + x4.y * w4.y + x4.z * w4.z + x4.w * w4.w;
        }
    }
    size_t obase = (size_t)blockIdx.x * 32 * C + wv * 8 * C + col;
    #pragma unroll
    for (int n = 0; n < 8; ++n) xw[obase + n * C] = f2bfu(acc[n]);
}

// ---- fused msg+update: wave per dst (best measured shape: ~68 us) ---------
// out = sigmoid( (Σ exp_e·xw[src_e]) / (Σ exp_e) + xw[d] + b )
__global__ __launch_bounds__(256) void k_msg_csr(
    const unsigned int* __restrict__ xw, const unsigned int* __restrict__ srt,
    const int* __restrict__ row_ptr, const void* __restrict__ b,
    const int* __restrict__ flags, void* __restrict__ outp, int out_is_final)
{
    int d = blockIdx.x * 4 + (threadIdx.x >> 6);
    int lane = threadIdx.x & 63;
    int half = lane >> 5, li = lane & 31;
    int beg = row_ptr[d], end = row_ptr[d + 1];
    float accx = 0.f, accy = 0.f, asum = 0.f;
    int j = beg;
    for (; j + 8 <= end; j += 8) {
        int jb = j + 4 * half;
        unsigned int p0 = __builtin_nontemporal_load(srt + jb);
        unsigned int p1 = __builtin_nontemporal_load(srt + jb + 1);
        unsigned int p2 = __builtin_nontemporal_load(srt + jb + 2);
        unsigned int p3 = __builtin_nontemporal_load(srt + jb + 3);
        unsigned int v0 = xw[(size_t)(p0 >> 15) * 32 + li];
        unsigned int v1 = xw[(size_t)(p1 >> 15) * 32 + li];
        unsigned int v2 = xw[(size_t)(p2 >> 15) * 32 + li];
        unsigned int v3 = xw[(size_t)(p3 >> 15) * 32 + li];
        float w0 = dec_w(p0), w1 = dec_w(p1), w2 = dec_w(p2), w3 = dec_w(p3);
        accx += w0 * blo(v0) + w1 * blo(v1) + w2 * blo(v2) + w3 * blo(v3);
        accy += w0 * bhi(v0) + w1 * bhi(v1) + w2 * bhi(v2) + w3 * bhi(v3);
        asum += (w0 + w1) + (w2 + w3);
    }
    if (j + 4 <= end) {                       // straight-line tails: 4, 2, 1
        int jb = j + 2 * half;
        unsigned int p0 = __builtin_nontemporal_load(srt + jb);
        unsigned int p1 = __builtin_nontemporal_load(srt + jb + 1);
        unsigned int v0 = xw[(size_t)(p0 >> 15) * 32 + li];
        unsigned int v1 = xw[(size_t)(p1 >> 15) * 32 + li];
        float w0 = dec_w(p0), w1 = dec_w(p1);
        accx += w0 * blo(v0) + w1 * blo(v1);
        accy += w0 * bhi(v0) + w1 * bhi(v1);
        asum += w0 + w1;
        j += 4;
    }
    if (j + 2 <= end) {
        unsigned int p0 = __builtin_nontemporal_load(srt + j + half);
        unsigned int v0 = xw[(size_t)(p0 >> 15) * 32 + li];
        float w0 = dec_w(p0);
        accx += w0 * blo(v0);
        accy += w0 * bhi(v0);
        asum += w0;
        j += 2;
    }
    if (j < end && half == 0) {
        unsigned int p0 = __builtin_nontemporal_load(srt + j);
        unsigned int v0 = xw[(size_t)(p0 >> 15) * 32 + li];
        float w0 = dec_w(p0);
        accx += w0 * blo(v0);
        accy += w0 * bhi(v0);
        asum += w0;
    }
    accx += __shfl_xor(accx, 32);
    accy += __shfl_xor(accy, 32);
    asum += __shfl_xor(asum, 32);
    float inv = (end > beg) ? 1.f / asum : 0.f;
    unsigned int sv = xw[(size_t)d * 32 + li];
    int f32 = flags[0];
    float b0 = load_f(b, 2 * li, f32), b1 = load_f(b, 2 * li + 1, f32);
    float v0 = accx * inv + blo(sv) + b0;
    float v1 = accy * inv + bhi(sv) + b1;
    float r0 = 1.f / (1.f + expf(-v0));
    float r1 = 1.f / (1.f + expf(-v1));
    if (half == 0) {
        if (out_is_final && f32) {
            vfloat2 rv; rv.x = r0; rv.y = r1;
            __builtin_nontemporal_store(rv, (vfloat2*)outp + (size_t)d * 32 + li);
        } else {
            unsigned int packed = (unsigned int)f2bfu(r0) | ((unsigned int)f2bfu(r1) << 16);
            __builtin_nontemporal_store(packed, (unsigned int*)outp + (size_t)d * 32 + li);
        }
    }
}

extern "C" void kernel_launch(void* const* d_in, const int* in_sizes, int n_in,
                              void* d_out, int out_size, void* d_ws, size_t ws_size,
                              hipStream_t stream) {
    const void* x  = d_in[0];
    const void* ei = d_in[1];
    const void* ea = d_in[2];
    const void* W1 = d_in[3];
    const void* b1 = d_in[4];
    const void* W2 = d_in[5];
    const void* b2 = d_in[6];

    char* base = (char*)d_ws;
    int*            flags   = (int*)base;                   // 256 B
    int*            gcnt    = (int*)(base + 256);           // 196 ints
    int*            colbase = (int*)(base + 1536);          // 197 ints
    int*            row_ptr = (int*)(base + 4096);          // N+1 ints
    unsigned int*   srt     = (unsigned int*)(base + 405504);    // E x 4B packed
    int2*           bkt     = (int2*)(base + 6805504);      // 196*9216*8 = 14.45 MB
    // bkt is dead after k_fine; xw/h1 overlay it:
    unsigned short* xw      = (unsigned short*)(base + 6805504);   // N*64 bf16
    unsigned short* h1      = (unsigned short*)(base + 19605504);  // N*64 bf16
    // total ws use ≈ 32.4 MB

    k_detect<<<1, 256, 0, stream>>>((const uint4*)x, (const int*)ei, flags);
    hipMemsetAsync(gcnt, 0, 1024, stream);

    // CSR build: bucketed counting sort (49K global atomics; LDS the rest)
    k_bucket<<<NBB, 256, 0, stream>>>(ea, ei, flags, gcnt, bkt);
    k_bktscan<<<1, 256, 0, stream>>>(gcnt, colbase, row_ptr);
    k_fine<<<NBKT, 256, 0, stream>>>(bkt, gcnt, colbase, row_ptr, srt);

    // layer 1 (internal node features bf16; xw overlays dead bkt)
    k_gemm1<<<N_NODES / 32, 256, 0, stream>>>(x, W1, flags, xw);
    k_msg_csr<<<N_NODES / 4, 256, 0, stream>>>((const unsigned int*)xw, srt, row_ptr, b1, flags, h1, 0);

    // layer 2
    k_gemm2<<<N_NODES / 32, 256, 0, stream>>>((const unsigned int*)h1, W2, flags, xw);
    k_msg_csr<<<N_NODES / 4, 256, 0, stream>>>((const unsigned int*)xw, srt, row_ptr, b2, flags, d_out, 1);
}

// Round 9
// 324.656 us; speedup vs baseline: 4.4216x; 1.0481x over previous
//
#include <hip/hip_runtime.h>
#include <hip/hip_bf16.h>

#define N_NODES 100000
#define N_EDGES 1600000
#define IN_C 128
#define C 64            // hid_c == out_c
#define NBKT 196        // coarse buckets: dst>>9 (512 dsts each)
#define CAP 9216        // bucket capacity: mean 8192, +11 sigma slack
#define BCHK 6400       // edges per bucket block (25/thread)
#define NBB (N_EDGES / BCHK)   // 250 bucket blocks
#define GB1 (N_NODES / 32)     // 3125 gemm1 blocks

typedef float vfloat2 __attribute__((ext_vector_type(2)));

__device__ __forceinline__ float bfu2f(unsigned short u) {
    return __uint_as_float(((unsigned int)u) << 16);
}
__device__ __forceinline__ unsigned short f2bfu(float f) {
    __hip_bfloat16 h = __float2bfloat16(f);
    unsigned short u; __builtin_memcpy(&u, &h, 2); return u;
}
// bf16x2 unpack, 1 VALU op each
__device__ __forceinline__ float blo(unsigned int v) { return __uint_as_float(v << 16); }
__device__ __forceinline__ float bhi(unsigned int v) { return __uint_as_float(v & 0xFFFF0000u); }
// 15-bit weight decode: w in [1, ~3.42), rel err ~3e-5
__device__ __forceinline__ float dec_w(unsigned int p) {
    return __uint_as_float(((p & 0x7FFFu) + 0x1FC000u) << 9);
}
__device__ __forceinline__ float load_f(const void* p, int i, int f32) {
    return f32 ? ((const float*)p)[i] : bfu2f(((const unsigned short*)p)[i]);
}
__device__ __forceinline__ int load_idx(const void* ei, size_t i, int i64) {
    return i64 ? (int)((const long long*)ei)[i] : ((const int*)ei)[i];
}

// ---- runtime dtype detection (counters confirmed fp32+int32) --------------
__global__ __launch_bounds__(256) void k_detect(
    const uint4* __restrict__ x4, const int* __restrict__ ei32,
    int* __restrict__ flags)
{
    __shared__ int cff, cnz;
    int t = threadIdx.x;
    if (t == 0) { cff = 0; cnz = 0; }
    __syncthreads();
    int lff = 0;
    #pragma unroll
    for (int j = 0; j < 16; ++j) {               // 16384 dwords of x
        uint4 w = x4[t + j * 256];
        unsigned int a[4] = {w.x, w.y, w.z, w.w};
        #pragma unroll
        for (int q = 0; q < 4; ++q) {
            // fp32 data: low mantissa half as pseudo-bf16 exponent hits 0xFF
            // w.p. 1/256 per dword; bf16 pairs never have exp==0xFF (no inf/NaN)
            if ((a[q] & 0x00007F80u) == 0x00007F80u) lff++;
            if ((a[q] & 0x7F800000u) == 0x7F800000u) lff++;
        }
    }
    int lnz = 0;
    for (int i = t; i < 2048; i += 256)
        if (ei32[2 * i + 1] != 0) lnz++;
    if (lff) atomicAdd(&cff, lff);
    if (lnz) atomicAdd(&cnz, lnz);
    __syncthreads();
    if (t == 0) {
        flags[0] = (cff > 0) ? 1 : 0;   // 1 = fp32 floats (confirmed on HW)
        flags[1] = (cnz == 0) ? 1 : 0;  // 1 = int64 indices (HW: int32)
    }
}

// ---- FAT kernel: blocks [0,NBB) = bucket sort; [NBB, NBB+GB1) = GEMM1 -----
// Bucket part: block-local LDS counting sort (fixes R8's scattered 8-B bucket
// writes -> coalesced ~208-B runs). GEMM1 part: independent of ei/ea, runs
// concurrently on the rest of the machine.
#define W1_STRIDE (IN_C + 4)   // 132
__global__ __launch_bounds__(256) void k_build_gemm1(
    const void* __restrict__ ea, const void* __restrict__ ei,
    const int* __restrict__ flags, int* __restrict__ gcnt,
    int2* __restrict__ bkt,
    const void* __restrict__ x, const void* __restrict__ W,
    unsigned short* __restrict__ xw)
{
    __shared__ __align__(16) char smem[56576];
    int t = threadIdx.x;
    if (blockIdx.x < NBB) {
        // ---------------- bucket portion ----------------
        int2* stage = (int2*)smem;                    // 6400 x 8B = 51200
        int*  h     = (int*)(smem + 51200);           // 256
        int*  ex    = (int*)(smem + 52224);           // 256
        int*  gb    = (int*)(smem + 53248);           // 256
        int*  ps    = (int*)(smem + 54272);           // 256
        int*  rk    = (int*)(smem + 55296);           // 256
        h[t] = 0; rk[t] = 0;
        __syncthreads();
        int i64 = flags[1], f32 = flags[0];
        int base = blockIdx.x * BCHK;
        for (int i = 0; i < 25; ++i) {               // pass A: histogram
            int e = base + i * 256 + t;
            int d = load_idx(ei, (size_t)N_EDGES + e, i64);
            atomicAdd(&h[d >> 9], 1);
        }
        __syncthreads();
        int hv = h[t];
        ps[t] = hv;
        for (int off = 1; off < 256; off <<= 1) {    // block scan of h
            __syncthreads();
            int val = (t >= off) ? ps[t - off] : 0;
            __syncthreads();
            ps[t] += val;
        }
        __syncthreads();
        ex[t] = ps[t] - hv;                          // exclusive prefix
        if (t < NBKT) gb[t] = atomicAdd(&gcnt[t], hv);
        __syncthreads();
        for (int i = 0; i < 25; ++i) {               // pass B: rank + stage
            int e = base + i * 256 + t;
            int d = load_idx(ei, (size_t)N_EDGES + e, i64);
            int s = load_idx(ei, (size_t)e, i64);
            float w = expf(load_f(ea, e, f32));      // unnormalized, [1, e)
            unsigned int wb = __float_as_uint(w);
            int wq = (int)((wb + 0x100u) >> 9) - 0x1FC000;   // 15-bit rnd
            wq = wq < 0 ? 0 : (wq > 0x7FFF ? 0x7FFF : wq);
            int bk2 = d >> 9;
            int r = atomicAdd(&rk[bk2], 1);
            stage[ex[bk2] + r] =
                make_int2((int)(((unsigned int)s << 15) | (unsigned int)wq), d);
        }
        __syncthreads();
        for (int i = 0; i < 25; ++i) {               // pass C: coalesced flush
            int idx = i * 256 + t;
            int2 r = stage[idx];
            int bk2 = ((unsigned int)r.y) >> 9;
            int lr = idx - ex[bk2];
            int gi = gb[bk2] + lr;
            if (gi < CAP)                            // fault insurance (+11 sigma)
                bkt[(size_t)bk2 * CAP + gi] = r;
        }
    } else {
        // ---------------- GEMM1 portion ----------------
        int bx = blockIdx.x - NBB;
        float* Wls = (float*)smem;                   // 64*132*4 = 33792
        float* xs  = (float*)(smem + 33792);         // 32*128*4 = 16384
        int f32 = flags[0];
        size_t xbase = (size_t)bx * 32 * IN_C;
        if (f32) {
            const float* xp = (const float*)x + xbase;
            #pragma unroll
            for (int j = 0; j < 16; ++j) { int i = t + j * 256; xs[i] = xp[i]; }
            const float* wp = (const float*)W;
            #pragma unroll
            for (int j = 0; j < 32; ++j) {
                int i = t + j * 256;
                Wls[(i >> 7) * W1_STRIDE + (i & 127)] = wp[i];
            }
        } else {
            const unsigned int* xp = (const unsigned int*)((const unsigned short*)x + xbase);
            #pragma unroll
            for (int j = 0; j < 8; ++j) {
                int i = t + j * 256;
                unsigned int v = xp[i];
                xs[2 * i]     = blo(v);
                xs[2 * i + 1] = bhi(v);
            }
            const unsigned short* wp = (const unsigned short*)W;
            #pragma unroll
            for (int j = 0; j < 32; ++j) {
                int i = t + j * 256;
                Wls[(i >> 7) * W1_STRIDE + (i & 127)] = bfu2f(wp[i]);
            }
        }
        __syncthreads();
        int col = t & 63, wv = t >> 6;
        const float* wr = Wls + col * W1_STRIDE;
        const float* xr = xs + wv * 8 * IN_C;
        float acc[8];
        #pragma unroll
        for (int n = 0; n < 8; ++n) acc[n] = 0.f;
        #pragma unroll
        for (int kk = 0; kk < IN_C / 4; ++kk) {
            float4 w4 = *(const float4*)(wr + kk * 4);
            #pragma unroll
            for (int n = 0; n < 8; ++n) {
                float4 x4 = *(const float4*)(xr + n * IN_C + kk * 4);
                acc[n] += x4.x * w4.x + x4.y * w4.y + x4.z * w4.z + x4.w * w4.w;
            }
        }
        size_t obase = (size_t)bx * 32 * C + wv * 8 * C + col;
        #pragma unroll
        for (int n = 0; n < 8; ++n) xw[obase + n * C] = f2bfu(acc[n]);
    }
}

// ---- CSR build pass 2: per-bucket fine sort (gcnt scan inlined) -----------
__global__ __launch_bounds__(256) void k_fine(
    const int2* __restrict__ bkt, const int* __restrict__ gcnt,
    int* __restrict__ row_ptr, unsigned int* __restrict__ srt)
{
    __shared__ int h[512], ex[512], ps[256];
    __shared__ int sh_cb;
    int t = threadIdx.x, b = blockIdx.x;
    // inline scan of gcnt[196] -> this block's colbase (replaces k_bktscan)
    int v = (t < NBKT) ? gcnt[t] : 0;
    ps[t] = v;
    for (int off = 1; off < 256; off <<= 1) {
        __syncthreads();
        int val = (t >= off) ? ps[t - off] : 0;
        __syncthreads();
        ps[t] += val;
    }
    __syncthreads();
    if (t == b) sh_cb = ps[t] - v;                   // b < 196 < 256
    if (b == 0 && t == 0) row_ptr[N_NODES] = N_EDGES;
    h[t] = 0; h[t + 256] = 0;
    __syncthreads();
    int nrec = gcnt[b];
    nrec = nrec < CAP ? nrec : CAP;                  // mirror of write clamp
    int cb = sh_cb;
    const int2* bp = bkt + (size_t)b * CAP;
    for (int i = t; i < nrec; i += 256)
        atomicAdd(&h[bp[i].y & 511], 1);
    __syncthreads();
    int s0 = h[2 * t], s1 = h[2 * t + 1];
    ps[t] = s0 + s1;
    for (int off = 1; off < 256; off <<= 1) {
        __syncthreads();
        int val = (t >= off) ? ps[t - off] : 0;
        __syncthreads();
        ps[t] += val;
    }
    __syncthreads();
    int pe = t ? ps[t - 1] : 0;
    ex[2 * t] = pe; ex[2 * t + 1] = pe + s0;
    __syncthreads();
    int d0 = b * 512 + t;
    if (d0 < N_NODES) row_ptr[d0] = cb + ex[t];
    int d1 = d0 + 256;
    if (d1 < N_NODES) row_ptr[d1] = cb + ex[t + 256];
    h[t] = 0; h[t + 256] = 0;                        // reuse h as rank counters
    __syncthreads();
    for (int i = t; i < nrec; i += 256) {
        int2 r = bp[i];
        int dl = r.y & 511;
        int rk = atomicAdd(&h[dl], 1);
        srt[cb + ex[dl] + rk] = (unsigned int)r.x;
    }
}

// ---- GEMM2: h (bf16 internal) @ W2 -> xw (bf16 internal) ------------------
#define W2_STRIDE (C + 4)      // 68
__global__ __launch_bounds__(256) void k_gemm2(
    const unsigned int* __restrict__ h, const void* __restrict__ W,
    const int* __restrict__ flags, unsigned short* __restrict__ xw)
{
    __shared__ float Wls[C * W2_STRIDE];
    __shared__ float xs[32 * C];
    int t = threadIdx.x;
    size_t dwbase = (size_t)blockIdx.x * 32 * 32;   // 32 rows x 32 dwords
    #pragma unroll
    for (int j = 0; j < 4; ++j) {
        int i = t + j * 256;
        unsigned int v = h[dwbase + i];
        xs[2 * i]     = blo(v);
        xs[2 * i + 1] = bhi(v);
    }
    if (flags[0]) {
        const float* wp = (const float*)W;
        #pragma unroll
        for (int j = 0; j < 16; ++j) {
            int i = t + j * 256;
            Wls[(i >> 6) * W2_STRIDE + (i & 63)] = wp[i];
        }
    } else {
        const unsigned short* wp = (const unsigned short*)W;
        #pragma unroll
        for (int j = 0; j < 16; ++j) {
            int i = t + j * 256;
            Wls[(i >> 6) * W2_STRIDE + (i & 63)] = bfu2f(wp[i]);
        }
    }
    __syncthreads();
    int col = t & 63, wv = t >> 6;
    const float* wr = Wls + col * W2_STRIDE;
    const float* xr = xs + wv * 8 * C;
    float acc[8];
    #pragma unroll
    for (int n = 0; n < 8; ++n) acc[n] = 0.f;
    #pragma unroll
    for (int kk = 0; kk < C / 4; ++kk) {
        float4 w4 = *(const float4*)(wr + kk * 4);
        #pragma unroll
        for (int n = 0; n < 8; ++n) {
            float4 x4 = *(const float4*)(xr + n * C + kk * 4);
            acc[n] += x4.x * w4.x + x4.y * w4.y + x4.z * w4.z + x4.w * w4.w;
        }
    }
    size_t obase = (size_t)blockIdx.x * 32 * C + wv * 8 * C + col;
    #pragma unroll
    for (int n = 0; n < 8; ++n) xw[obase + n * C] = f2bfu(acc[n]);
}

// ---- fused msg+update: wave per dst (best measured shape: ~65 us) ---------
// out = sigmoid( (Σ exp_e·xw[src_e]) / (Σ exp_e) + xw[d] + b )
__global__ __launch_bounds__(256) void k_msg_csr(
    const unsigned int* __restrict__ xw, const unsigned int* __restrict__ srt,
    const int* __restrict__ row_ptr, const void* __restrict__ b,
    const int* __restrict__ flags, void* __restrict__ outp, int out_is_final)
{
    int d = blockIdx.x * 4 + (threadIdx.x >> 6);
    int lane = threadIdx.x & 63;
    int half = lane >> 5, li = lane & 31;
    int beg = row_ptr[d], end = row_ptr[d + 1];
    float accx = 0.f, accy = 0.f, asum = 0.f;
    int j = beg;
    for (; j + 8 <= end; j += 8) {
        int jb = j + 4 * half;
        unsigned int p0 = __builtin_nontemporal_load(srt + jb);
        unsigned int p1 = __builtin_nontemporal_load(srt + jb + 1);
        unsigned int p2 = __builtin_nontemporal_load(srt + jb + 2);
        unsigned int p3 = __builtin_nontemporal_load(srt + jb + 3);
        unsigned int v0 = xw[(size_t)(p0 >> 15) * 32 + li];
        unsigned int v1 = xw[(size_t)(p1 >> 15) * 32 + li];
        unsigned int v2 = xw[(size_t)(p2 >> 15) * 32 + li];
        unsigned int v3 = xw[(size_t)(p3 >> 15) * 32 + li];
        float w0 = dec_w(p0), w1 = dec_w(p1), w2 = dec_w(p2), w3 = dec_w(p3);
        accx += w0 * blo(v0) + w1 * blo(v1) + w2 * blo(v2) + w3 * blo(v3);
        accy += w0 * bhi(v0) + w1 * bhi(v1) + w2 * bhi(v2) + w3 * bhi(v3);
        asum += (w0 + w1) + (w2 + w3);
    }
    if (j + 4 <= end) {                       // straight-line tails: 4, 2, 1
        int jb = j + 2 * half;
        unsigned int p0 = __builtin_nontemporal_load(srt + jb);
        unsigned int p1 = __builtin_nontemporal_load(srt + jb + 1);
        unsigned int v0 = xw[(size_t)(p0 >> 15) * 32 + li];
        unsigned int v1 = xw[(size_t)(p1 >> 15) * 32 + li];
        float w0 = dec_w(p0), w1 = dec_w(p1);
        accx += w0 * blo(v0) + w1 * blo(v1);
        accy += w0 * bhi(v0) + w1 * bhi(v1);
        asum += w0 + w1;
        j += 4;
    }
    if (j + 2 <= end) {
        unsigned int p0 = __builtin_nontemporal_load(srt + j + half);
        unsigned int v0 = xw[(size_t)(p0 >> 15) * 32 + li];
        float w0 = dec_w(p0);
        accx += w0 * blo(v0);
        accy += w0 * bhi(v0);
        asum += w0;
        j += 2;
    }
    if (j < end && half == 0) {
        unsigned int p0 = __builtin_nontemporal_load(srt + j);
        unsigned int v0 = xw[(size_t)(p0 >> 15) * 32 + li];
        float w0 = dec_w(p0);
        accx += w0 * blo(v0);
        accy += w0 * bhi(v0);
        asum += w0;
    }
    accx += __shfl_xor(accx, 32);
    accy += __shfl_xor(accy, 32);
    asum += __shfl_xor(asum, 32);
    float inv = (end > beg) ? 1.f / asum : 0.f;
    unsigned int sv = xw[(size_t)d * 32 + li];
    int f32 = flags[0];
    float b0 = load_f(b, 2 * li, f32), b1 = load_f(b, 2 * li + 1, f32);
    float v0 = accx * inv + blo(sv) + b0;
    float v1 = accy * inv + bhi(sv) + b1;
    float r0 = 1.f / (1.f + expf(-v0));
    float r1 = 1.f / (1.f + expf(-v1));
    if (half == 0) {
        if (out_is_final && f32) {
            vfloat2 rv; rv.x = r0; rv.y = r1;
            __builtin_nontemporal_store(rv, (vfloat2*)outp + (size_t)d * 32 + li);
        } else {
            unsigned int packed = (unsigned int)f2bfu(r0) | ((unsigned int)f2bfu(r1) << 16);
            __builtin_nontemporal_store(packed, (unsigned int*)outp + (size_t)d * 32 + li);
        }
    }
}

extern "C" void kernel_launch(void* const* d_in, const int* in_sizes, int n_in,
                              void* d_out, int out_size, void* d_ws, size_t ws_size,
                              hipStream_t stream) {
    const void* x  = d_in[0];
    const void* ei = d_in[1];
    const void* ea = d_in[2];
    const void* W1 = d_in[3];
    const void* b1 = d_in[4];
    const void* W2 = d_in[5];
    const void* b2 = d_in[6];

    char* base = (char*)d_ws;
    int*            flags   = (int*)base;                   // 256 B
    int*            gcnt    = (int*)(base + 256);           // 196 ints
    int*            row_ptr = (int*)(base + 4096);          // N+1 ints
    unsigned int*   srt     = (unsigned int*)(base + 405504);    // E x 4B packed
    int2*           bkt     = (int2*)(base + 6805504);      // 196*9216*8 = 14.45 MB
    // bkt is dead after k_fine; h1 overlays it. xw is concurrent with bkt
    // (fat kernel) so it gets its own space.
    unsigned short* h1      = (unsigned short*)(base + 6805504);   // N*64 bf16
    unsigned short* xw      = (unsigned short*)(base + 21256192);  // N*64 bf16
    // total ws use ≈ 34.1 MB

    k_detect<<<1, 256, 0, stream>>>((const uint4*)x, (const int*)ei, flags);
    hipMemsetAsync(gcnt, 0, 1024, stream);

    // [bucket sort ∥ GEMM1] in one fat launch, then fine sort (scan inlined)
    k_build_gemm1<<<NBB + GB1, 256, 0, stream>>>(ea, ei, flags, gcnt, bkt,
                                                 x, W1, xw);
    k_fine<<<NBKT, 256, 0, stream>>>(bkt, gcnt, row_ptr, srt);

    // layer 1 (h1 overlays dead bkt)
    k_msg_csr<<<N_NODES / 4, 256, 0, stream>>>((const unsigned int*)xw, srt, row_ptr, b1, flags, h1, 0);

    // layer 2
    k_gemm2<<<N_NODES / 32, 256, 0, stream>>>((const unsigned int*)h1, W2, flags, xw);
    k_msg_csr<<<N_NODES / 4, 256, 0, stream>>>((const unsigned int*)xw, srt, row_ptr, b2, flags, d_out, 1);
}

// Round 10
// 316.043 us; speedup vs baseline: 4.5421x; 1.0273x over previous
//
#include <hip/hip_runtime.h>
#include <hip/hip_bf16.h>

#define N_NODES 100000
#define N_EDGES 1600000
#define IN_C 128
#define C 64            // hid_c == out_c
#define NBKT 196        // coarse buckets: dst>>9 (512 dsts each)
#define CAP 9216        // bucket capacity: mean 8192, +11 sigma slack
#define BCHK 4000       // edges per bucket block (LDS diet: 32 KB stage)
#define NBB (N_EDGES / BCHK)   // 400 bucket blocks
#define GB1 (N_NODES / 32)     // 3125 gemm1 blocks

typedef float vfloat2 __attribute__((ext_vector_type(2)));

__device__ __forceinline__ float bfu2f(unsigned short u) {
    return __uint_as_float(((unsigned int)u) << 16);
}
__device__ __forceinline__ unsigned short f2bfu(float f) {
    __hip_bfloat16 h = __float2bfloat16(f);
    unsigned short u; __builtin_memcpy(&u, &h, 2); return u;
}
// bf16x2 unpack, 1 VALU op each
__device__ __forceinline__ float blo(unsigned int v) { return __uint_as_float(v << 16); }
__device__ __forceinline__ float bhi(unsigned int v) { return __uint_as_float(v & 0xFFFF0000u); }
// 15-bit weight decode: w in [1, ~3.42), rel err ~3e-5
__device__ __forceinline__ float dec_w(unsigned int p) {
    return __uint_as_float(((p & 0x7FFFu) + 0x1FC000u) << 9);
}
__device__ __forceinline__ float load_f(const void* p, int i, int f32) {
    return f32 ? ((const float*)p)[i] : bfu2f(((const unsigned short*)p)[i]);
}
__device__ __forceinline__ int load_idx(const void* ei, size_t i, int i64) {
    return i64 ? (int)((const long long*)ei)[i] : ((const int*)ei)[i];
}

// ---- runtime dtype detection + gcnt zeroing (saves a memset launch) -------
__global__ __launch_bounds__(256) void k_detect(
    const uint4* __restrict__ x4, const int* __restrict__ ei32,
    int* __restrict__ flags, int* __restrict__ gcnt)
{
    __shared__ int cff, cnz;
    int t = threadIdx.x;
    gcnt[t] = 0;                                 // 256 ints >= NBKT
    if (t == 0) { cff = 0; cnz = 0; }
    __syncthreads();
    int lff = 0;
    #pragma unroll
    for (int j = 0; j < 16; ++j) {               // 16384 dwords of x
        uint4 w = x4[t + j * 256];
        unsigned int a[4] = {w.x, w.y, w.z, w.w};
        #pragma unroll
        for (int q = 0; q < 4; ++q) {
            // fp32 data: low mantissa half as pseudo-bf16 exponent hits 0xFF
            // w.p. 1/256 per dword; bf16 pairs never have exp==0xFF (no inf/NaN)
            if ((a[q] & 0x00007F80u) == 0x00007F80u) lff++;
            if ((a[q] & 0x7F800000u) == 0x7F800000u) lff++;
        }
    }
    int lnz = 0;
    for (int i = t; i < 2048; i += 256)
        if (ei32[2 * i + 1] != 0) lnz++;
    if (lff) atomicAdd(&cff, lff);
    if (lnz) atomicAdd(&cnz, lnz);
    __syncthreads();
    if (t == 0) {
        flags[0] = (cff > 0) ? 1 : 0;   // 1 = fp32 floats (confirmed on HW)
        flags[1] = (cnz == 0) ? 1 : 0;  // 1 = int64 indices (HW: int32)
    }
}

// ---- FAT kernel: blocks [0,NBB) = bucket sort; [NBB, NBB+GB1) = GEMM1 -----
// LDS diet (R9: 56.8 KB -> 2 blk/CU -> 19% occupancy was the binder):
//   bucket: BCHK 4000 -> 32 KB stage + 5 KB aux = 37.1 KB
//   gemm1:  W cols in 2 halves -> 16.4 (xs) + 16.9 (Wls half) = 33.3 KB
// Union 37.1 KB -> 4 blocks/CU.
#define W1_STRIDE (IN_C + 4)   // 132
__global__ __launch_bounds__(256) void k_build_gemm1(
    const void* __restrict__ ea, const void* __restrict__ ei,
    const int* __restrict__ flags, int* __restrict__ gcnt,
    int2* __restrict__ bkt,
    const void* __restrict__ x, const void* __restrict__ W,
    unsigned short* __restrict__ xw)
{
    __shared__ __align__(16) char smem[37120];
    int t = threadIdx.x;
    if (blockIdx.x < NBB) {
        // ---------------- bucket portion ----------------
        int2* stage = (int2*)smem;                    // 4000 x 8B = 32000
        int*  h     = (int*)(smem + 32000);           // 256
        int*  ex    = (int*)(smem + 33024);           // 256
        int*  gb    = (int*)(smem + 34048);           // 256
        int*  ps    = (int*)(smem + 35072);           // 256
        int*  rk    = (int*)(smem + 36096);           // 256
        h[t] = 0; rk[t] = 0;
        __syncthreads();
        int i64 = flags[1], f32 = flags[0];
        int base = blockIdx.x * BCHK;
        #pragma unroll
        for (int i = 0; i < 16; ++i) {               // pass A: histogram
            int ii = i * 256 + t;
            if (ii < BCHK) {
                int d = load_idx(ei, (size_t)N_EDGES + base + ii, i64);
                atomicAdd(&h[d >> 9], 1);
            }
        }
        __syncthreads();
        int hv = h[t];
        ps[t] = hv;
        for (int off = 1; off < 256; off <<= 1) {    // block scan of h
            __syncthreads();
            int val = (t >= off) ? ps[t - off] : 0;
            __syncthreads();
            ps[t] += val;
        }
        __syncthreads();
        ex[t] = ps[t] - hv;                          // exclusive prefix
        if (t < NBKT) gb[t] = atomicAdd(&gcnt[t], hv);
        __syncthreads();
        #pragma unroll
        for (int i = 0; i < 16; ++i) {               // pass B: rank + stage
            int ii = i * 256 + t;
            if (ii < BCHK) {
                int e = base + ii;
                int d = load_idx(ei, (size_t)N_EDGES + e, i64);
                int s = load_idx(ei, (size_t)e, i64);
                float w = expf(load_f(ea, e, f32));  // unnormalized, [1, e)
                unsigned int wb = __float_as_uint(w);
                int wq = (int)((wb + 0x100u) >> 9) - 0x1FC000;   // 15-bit rnd
                wq = wq < 0 ? 0 : (wq > 0x7FFF ? 0x7FFF : wq);
                int bk2 = d >> 9;
                int r = atomicAdd(&rk[bk2], 1);
                stage[ex[bk2] + r] =
                    make_int2((int)(((unsigned int)s << 15) | (unsigned int)wq), d);
            }
        }
        __syncthreads();
        #pragma unroll
        for (int i = 0; i < 16; ++i) {               // pass C: coalesced flush
            int idx = i * 256 + t;
            if (idx < BCHK) {
                int2 r = stage[idx];
                int bk2 = ((unsigned int)r.y) >> 9;
                int lr = idx - ex[bk2];
                int gi = gb[bk2] + lr;
                if (gi < CAP)                        // fault insurance (+11 sigma)
                    bkt[(size_t)bk2 * CAP + gi] = r;
            }
        }
    } else {
        // ---------------- GEMM1 portion (2 col-halves) ----------------
        int bx = blockIdx.x - NBB;
        float* xs  = (float*)smem;                   // 32*128*4 = 16384
        float* Wls = (float*)(smem + 16384);         // 32*132*4 = 16896
        int f32 = flags[0];
        size_t xbase = (size_t)bx * 32 * IN_C;
        if (f32) {
            const float* xp = (const float*)x + xbase;
            #pragma unroll
            for (int j = 0; j < 16; ++j) { int i = t + j * 256; xs[i] = xp[i]; }
        } else {
            const unsigned int* xp = (const unsigned int*)((const unsigned short*)x + xbase);
            #pragma unroll
            for (int j = 0; j < 8; ++j) {
                int i = t + j * 256;
                unsigned int v = xp[i];
                xs[2 * i]     = blo(v);
                xs[2 * i + 1] = bhi(v);
            }
        }
        int col = t & 31, wv = t >> 5;               // 8 row-groups x 4 rows
        #pragma unroll
        for (int hf = 0; hf < 2; ++hf) {
            __syncthreads();                         // prev half done w/ Wls
            if (f32) {
                const float* wp = (const float*)W + hf * 32 * IN_C;
                #pragma unroll
                for (int j = 0; j < 16; ++j) {
                    int i = t + j * 256;             // 0..4095
                    Wls[(i >> 7) * W1_STRIDE + (i & 127)] = wp[i];
                }
            } else {
                const unsigned short* wp = (const unsigned short*)W + hf * 32 * IN_C;
                #pragma unroll
                for (int j = 0; j < 16; ++j) {
                    int i = t + j * 256;
                    Wls[(i >> 7) * W1_STRIDE + (i & 127)] = bfu2f(wp[i]);
                }
            }
            __syncthreads();                         // Wls (and xs) visible
            const float* wr = Wls + col * W1_STRIDE;
            const float* xr = xs + wv * 4 * IN_C;
            float acc[4];
            #pragma unroll
            for (int n = 0; n < 4; ++n) acc[n] = 0.f;
            #pragma unroll
            for (int kk = 0; kk < IN_C / 4; ++kk) {
                float4 w4 = *(const float4*)(wr + kk * 4);
                #pragma unroll
                for (int n = 0; n < 4; ++n) {
                    float4 x4 = *(const float4*)(xr + n * IN_C + kk * 4);
                    acc[n] += x4.x * w4.x + x4.y * w4.y + x4.z * w4.z + x4.w * w4.w;
                }
            }
            size_t obase = (size_t)bx * 32 * C + wv * 4 * C + hf * 32 + col;
            #pragma unroll
            for (int n = 0; n < 4; ++n) xw[obase + n * C] = f2bfu(acc[n]);
        }
    }
}

// ---- CSR build pass 2: per-bucket fine sort (gcnt scan inlined) -----------
__global__ __launch_bounds__(256) void k_fine(
    const int2* __restrict__ bkt, const int* __restrict__ gcnt,
    int* __restrict__ row_ptr, unsigned int* __restrict__ srt)
{
    __shared__ int h[512], ex[512], ps[256];
    __shared__ int sh_cb;
    int t = threadIdx.x, b = blockIdx.x;
    // inline scan of gcnt[196] -> this block's colbase (replaces k_bktscan)
    int v = (t < NBKT) ? gcnt[t] : 0;
    ps[t] = v;
    for (int off = 1; off < 256; off <<= 1) {
        __syncthreads();
        int val = (t >= off) ? ps[t - off] : 0;
        __syncthreads();
        ps[t] += val;
    }
    __syncthreads();
    if (t == b) sh_cb = ps[t] - v;                   // b < 196 < 256
    if (b == 0 && t == 0) row_ptr[N_NODES] = N_EDGES;
    h[t] = 0; h[t + 256] = 0;
    __syncthreads();
    int nrec = gcnt[b];
    nrec = nrec < CAP ? nrec : CAP;                  // mirror of write clamp
    int cb = sh_cb;
    const int2* bp = bkt + (size_t)b * CAP;
    for (int i = t; i < nrec; i += 256)
        atomicAdd(&h[bp[i].y & 511], 1);
    __syncthreads();
    int s0 = h[2 * t], s1 = h[2 * t + 1];
    ps[t] = s0 + s1;
    for (int off = 1; off < 256; off <<= 1) {
        __syncthreads();
        int val = (t >= off) ? ps[t - off] : 0;
        __syncthreads();
        ps[t] += val;
    }
    __syncthreads();
    int pe = t ? ps[t - 1] : 0;
    ex[2 * t] = pe; ex[2 * t + 1] = pe + s0;
    __syncthreads();
    int d0 = b * 512 + t;
    if (d0 < N_NODES) row_ptr[d0] = cb + ex[t];
    int d1 = d0 + 256;
    if (d1 < N_NODES) row_ptr[d1] = cb + ex[t + 256];
    h[t] = 0; h[t + 256] = 0;                        // reuse h as rank counters
    __syncthreads();
    for (int i = t; i < nrec; i += 256) {
        int2 r = bp[i];
        int dl = r.y & 511;
        int rk = atomicAdd(&h[dl], 1);
        srt[cb + ex[dl] + rk] = (unsigned int)r.x;
    }
}

// ---- GEMM2: h (bf16 internal) @ W2 -> xw (bf16 internal) ------------------
#define W2_STRIDE (C + 4)      // 68
__global__ __launch_bounds__(256) void k_gemm2(
    const unsigned int* __restrict__ h, const void* __restrict__ W,
    const int* __restrict__ flags, unsigned short* __restrict__ xw)
{
    __shared__ float Wls[C * W2_STRIDE];
    __shared__ float xs[32 * C];
    int t = threadIdx.x;
    size_t dwbase = (size_t)blockIdx.x * 32 * 32;   // 32 rows x 32 dwords
    #pragma unroll
    for (int j = 0; j < 4; ++j) {
        int i = t + j * 256;
        unsigned int v = h[dwbase + i];
        xs[2 * i]     = blo(v);
        xs[2 * i + 1] = bhi(v);
    }
    if (flags[0]) {
        const float* wp = (const float*)W;
        #pragma unroll
        for (int j = 0; j < 16; ++j) {
            int i = t + j * 256;
            Wls[(i >> 6) * W2_STRIDE + (i & 63)] = wp[i];
        }
    } else {
        const unsigned short* wp = (const unsigned short*)W;
        #pragma unroll
        for (int j = 0; j < 16; ++j) {
            int i = t + j * 256;
            Wls[(i >> 6) * W2_STRIDE + (i & 63)] = bfu2f(wp[i]);
        }
    }
    __syncthreads();
    int col = t & 63, wv = t >> 6;
    const float* wr = Wls + col * W2_STRIDE;
    const float* xr = xs + wv * 8 * C;
    float acc[8];
    #pragma unroll
    for (int n = 0; n < 8; ++n) acc[n] = 0.f;
    #pragma unroll
    for (int kk = 0; kk < C / 4; ++kk) {
        float4 w4 = *(const float4*)(wr + kk * 4);
        #pragma unroll
        for (int n = 0; n < 8; ++n) {
            float4 x4 = *(const float4*)(xr + n * C + kk * 4);
            acc[n] += x4.x * w4.x + x4.y * w4.y + x4.z * w4.z + x4.w * w4.w;
        }
    }
    size_t obase = (size_t)blockIdx.x * 32 * C + wv * 8 * C + col;
    #pragma unroll
    for (int n = 0; n < 8; ++n) xw[obase + n * C] = f2bfu(acc[n]);
}

// ---- fused msg+update: wave per dst (best measured shape: ~65 us) ---------
// out = sigmoid( (Σ exp_e·xw[src_e]) / (Σ exp_e) + xw[d] + b )
__global__ __launch_bounds__(256) void k_msg_csr(
    const unsigned int* __restrict__ xw, const unsigned int* __restrict__ srt,
    const int* __restrict__ row_ptr, const void* __restrict__ b,
    const int* __restrict__ flags, void* __restrict__ outp, int out_is_final)
{
    int d = blockIdx.x * 4 + (threadIdx.x >> 6);
    int lane = threadIdx.x & 63;
    int half = lane >> 5, li = lane & 31;
    int beg = row_ptr[d], end = row_ptr[d + 1];
    float accx = 0.f, accy = 0.f, asum = 0.f;
    int j = beg;
    for (; j + 8 <= end; j += 8) {
        int jb = j + 4 * half;
        unsigned int p0 = __builtin_nontemporal_load(srt + jb);
        unsigned int p1 = __builtin_nontemporal_load(srt + jb + 1);
        unsigned int p2 = __builtin_nontemporal_load(srt + jb + 2);
        unsigned int p3 = __builtin_nontemporal_load(srt + jb + 3);
        unsigned int v0 = xw[(size_t)(p0 >> 15) * 32 + li];
        unsigned int v1 = xw[(size_t)(p1 >> 15) * 32 + li];
        unsigned int v2 = xw[(size_t)(p2 >> 15) * 32 + li];
        unsigned int v3 = xw[(size_t)(p3 >> 15) * 32 + li];
        float w0 = dec_w(p0), w1 = dec_w(p1), w2 = dec_w(p2), w3 = dec_w(p3);
        accx += w0 * blo(v0) + w1 * blo(v1) + w2 * blo(v2) + w3 * blo(v3);
        accy += w0 * bhi(v0) + w1 * bhi(v1) + w2 * bhi(v2) + w3 * bhi(v3);
        asum += (w0 + w1) + (w2 + w3);
    }
    if (j + 4 <= end) {                       // straight-line tails: 4, 2, 1
        int jb = j + 2 * half;
        unsigned int p0 = __builtin_nontemporal_load(srt + jb);
        unsigned int p1 = __builtin_nontemporal_load(srt + jb + 1);
        unsigned int v0 = xw[(size_t)(p0 >> 15) * 32 + li];
        unsigned int v1 = xw[(size_t)(p1 >> 15) * 32 + li];
        float w0 = dec_w(p0), w1 = dec_w(p1);
        accx += w0 * blo(v0) + w1 * blo(v1);
        accy += w0 * bhi(v0) + w1 * bhi(v1);
        asum += w0 + w1;
        j += 4;
    }
    if (j + 2 <= end) {
        unsigned int p0 = __builtin_nontemporal_load(srt + j + half);
        unsigned int v0 = xw[(size_t)(p0 >> 15) * 32 + li];
        float w0 = dec_w(p0);
        accx += w0 * blo(v0);
        accy += w0 * bhi(v0);
        asum += w0;
        j += 2;
    }
    if (j < end && half == 0) {
        unsigned int p0 = __builtin_nontemporal_load(srt + j);
        unsigned int v0 = xw[(size_t)(p0 >> 15) * 32 + li];
        float w0 = dec_w(p0);
        accx += w0 * blo(v0);
        accy += w0 * bhi(v0);
        asum += w0;
    }
    accx += __shfl_xor(accx, 32);
    accy += __shfl_xor(accy, 32);
    asum += __shfl_xor(asum, 32);
    float inv = (end > beg) ? 1.f / asum : 0.f;
    unsigned int sv = xw[(size_t)d * 32 + li];
    int f32 = flags[0];
    float b0 = load_f(b, 2 * li, f32), b1 = load_f(b, 2 * li + 1, f32);
    float v0 = accx * inv + blo(sv) + b0;
    float v1 = accy * inv + bhi(sv) + b1;
    float r0 = 1.f / (1.f + expf(-v0));
    float r1 = 1.f / (1.f + expf(-v1));
    if (half == 0) {
        if (out_is_final && f32) {
            vfloat2 rv; rv.x = r0; rv.y = r1;
            __builtin_nontemporal_store(rv, (vfloat2*)outp + (size_t)d * 32 + li);
        } else {
            unsigned int packed = (unsigned int)f2bfu(r0) | ((unsigned int)f2bfu(r1) << 16);
            __builtin_nontemporal_store(packed, (unsigned int*)outp + (size_t)d * 32 + li);
        }
    }
}

extern "C" void kernel_launch(void* const* d_in, const int* in_sizes, int n_in,
                              void* d_out, int out_size, void* d_ws, size_t ws_size,
                              hipStream_t stream) {
    const void* x  = d_in[0];
    const void* ei = d_in[1];
    const void* ea = d_in[2];
    const void* W1 = d_in[3];
    const void* b1 = d_in[4];
    const void* W2 = d_in[5];
    const void* b2 = d_in[6];

    char* base = (char*)d_ws;
    int*            flags   = (int*)base;                   // 256 B
    int*            gcnt    = (int*)(base + 256);           // 256 ints
    int*            row_ptr = (int*)(base + 4096);          // N+1 ints
    unsigned int*   srt     = (unsigned int*)(base + 405504);    // E x 4B packed
    int2*           bkt     = (int2*)(base + 6805504);      // 196*9216*8 = 14.45 MB
    // bkt is dead after k_fine; h1 overlays it. xw is concurrent with bkt
    // (fat kernel) so it gets its own space.
    unsigned short* h1      = (unsigned short*)(base + 6805504);   // N*64 bf16
    unsigned short* xw      = (unsigned short*)(base + 21256192);  // N*64 bf16
    // total ws use ≈ 34.1 MB

    k_detect<<<1, 256, 0, stream>>>((const uint4*)x, (const int*)ei, flags, gcnt);

    // [bucket sort ∥ GEMM1] in one fat launch, then fine sort (scan inlined)
    k_build_gemm1<<<NBB + GB1, 256, 0, stream>>>(ea, ei, flags, gcnt, bkt,
                                                 x, W1, xw);
    k_fine<<<NBKT, 256, 0, stream>>>(bkt, gcnt, row_ptr, srt);

    // layer 1 (h1 overlays dead bkt)
    k_msg_csr<<<N_NODES / 4, 256, 0, stream>>>((const unsigned int*)xw, srt, row_ptr, b1, flags, h1, 0);

    // layer 2
    k_gemm2<<<N_NODES / 32, 256, 0, stream>>>((const unsigned int*)h1, W2, flags, xw);
    k_msg_csr<<<N_NODES / 4, 256, 0, stream>>>((const unsigned int*)xw, srt, row_ptr, b2, flags, d_out, 1);
}